// Round 9
// baseline (525.971 us; speedup 1.0000x reference)
//
#include <hip/hip_runtime.h>
#include <hip/hip_fp16.h>
#include <stdint.h>

typedef _Float16 f16;
typedef _Float16 f16x8 __attribute__((ext_vector_type(8)));
typedef _Float16 f16x4 __attribute__((ext_vector_type(4)));
typedef _Float16 f16x2 __attribute__((ext_vector_type(2)));
typedef float f32x4 __attribute__((ext_vector_type(4)));
typedef float f32x2 __attribute__((ext_vector_type(2)));

#define B_ 4
#define N_ 16384
#define M_ 4096
#define C1_ 128
#define C2_ 256
#define BNTOT 65536  // B_*N_

#define SPLIT 16
#define CHUNK (M_ / SPLIT)  // 256
#define QPT 4               // queries per thread in nn_part (register-blocked)

// ---------------- async global->LDS 16B ----------------
__device__ __forceinline__ void gload_lds16(const void* g, void* l) {
    __builtin_amdgcn_global_load_lds(
        (const __attribute__((address_space(1))) void*)g,
        (__attribute__((address_space(3))) void*)l, 16, 0, 0);
}

// exact branchy top-3 insert (R2-proven; strict < == lax.top_k tie-break)
#define NN_INSERT(k0, k1, k2, i0, i1, i2, d2, mi)                          \
    if (d2 < k2) {                                                         \
        if (d2 < k1) {                                                     \
            k2 = k1; i2 = i1;                                              \
            if (d2 < k0) { k1 = k0; i1 = i0; k0 = d2; i0 = mi; }           \
            else         { k1 = d2; i1 = mi; }                             \
        } else { k2 = d2; i2 = mi; }                                       \
    }

// ---------------- kernel: fp32 -> fp16 weights + zero stats buffers ----------------
__global__ void conv_f16_kernel(const float* __restrict__ s0, f16* __restrict__ d0,
                                const float* __restrict__ s1, f16* __restrict__ d1,
                                const float* __restrict__ s2, f16* __restrict__ d2,
                                float* __restrict__ statz) {
    int i = blockIdx.x * blockDim.x + threadIdx.x;
    if (i < 98304) d0[i] = (f16)s0[i];
    if (i < 65536) d1[i] = (f16)s1[i];
    if (i < 32768) d2[i] = (f16)s2[i];
    if (i < 1536) statz[i] = 0.0f;   // 3 layers x (sums[256], sumsq[256])
}

// ---------------- kernel: 3-NN partial search over one M-chunk ----------------
// EXACT fp32 d2 compares (packed-key truncation fatal in R5). QPT=4 queries
// per thread: the 3 ds_read_b128 per 4 candidates amortize over 16 evals
// (LDS issue 9 -> 2.25 cy/eval). Direct squared-diff (no cancellation).
__global__ __launch_bounds__(256) void nn_part_kernel(
    const float* __restrict__ xyz1, const float* __restrict__ xyz2,
    f32x2* __restrict__ ck) {
    __shared__ __align__(16) float xs[CHUNK];
    __shared__ __align__(16) float ys[CHUNK];
    __shared__ __align__(16) float zs[CHUNK];
    int bid = blockIdx.x;                // grid = (BNTOT/1024) * SPLIT = 1024
    int part = bid & (SPLIT - 1);
    int pblk = bid >> 4;                 // 0..63, 1024 queries each
    int b = pblk >> 4;                   // 16 point-blocks per batch
    int m0 = part * CHUNK;
    const float* x2 = xyz2 + ((size_t)b * M_ + m0) * 3;
    {
        int m = threadIdx.x;  // CHUNK == blockDim.x
        xs[m] = x2[m * 3 + 0];
        ys[m] = x2[m * 3 + 1];
        zs[m] = x2[m * 3 + 2];
    }
    __syncthreads();
    size_t p0 = (size_t)pblk * 1024 + threadIdx.x;  // queries p0 + q*256, q=0..3
    float qx[QPT], qy[QPT], qz[QPT];
#pragma unroll
    for (int q = 0; q < QPT; ++q) {
        const float* qp = xyz1 + (p0 + q * 256) * 3;
        qx[q] = qp[0]; qy[q] = qp[1]; qz[q] = qp[2];
    }
    float k0[QPT], k1[QPT], k2[QPT];
    int i0[QPT], i1[QPT], i2[QPT];
#pragma unroll
    for (int q = 0; q < QPT; ++q) {
        k0[q] = 3.4e38f; k1[q] = 3.4e38f; k2[q] = 3.4e38f;
        i0[q] = 0; i1[q] = 0; i2[q] = 0;
    }
    for (int m = 0; m < CHUNK; m += 4) {
        f32x4 xv = *(const f32x4*)&xs[m];   // uniform addr -> LDS broadcast
        f32x4 yv = *(const f32x4*)&ys[m];
        f32x4 zv = *(const f32x4*)&zs[m];
#pragma unroll
        for (int u = 0; u < 4; ++u) {
            float cx = xv[u], cy = yv[u], cz = zv[u];
            int mi = m0 + m + u;
#pragma unroll
            for (int q = 0; q < QPT; ++q) {
                float dx = qx[q] - cx, dy = qy[q] - cy, dz = qz[q] - cz;
                float d2 = fmaf(dx, dx, fmaf(dy, dy, dz * dz));
                NN_INSERT(k0[q], k1[q], k2[q], i0[q], i1[q], i2[q], d2, mi)
            }
        }
    }
    // rank-major [rank][part][point] -> each store fully coalesced (8B/lane)
#pragma unroll
    for (int q = 0; q < QPT; ++q) {
        size_t p = p0 + q * 256;
        f32x2 e0 = {k0[q], __int_as_float(i0[q])};
        f32x2 e1 = {k1[q], __int_as_float(i1[q])};
        f32x2 e2 = {k2[q], __int_as_float(i2[q])};
        __builtin_nontemporal_store(e0, ck + (size_t)(0 * SPLIT + part) * BNTOT + p);
        __builtin_nontemporal_store(e1, ck + (size_t)(1 * SPLIT + part) * BNTOT + p);
        __builtin_nontemporal_store(e2, ck + (size_t)(2 * SPLIT + part) * BNTOT + p);
    }
}

// ---------------- kernel: merge SPLIT x 3 candidates -> top-3 + weights ----------------
// Parts ascending, ranks ascending within part, strict < insertion ->
// identical result/tie-break to one sequential ascending-index scan.
__global__ __launch_bounds__(256) void nn_merge_kernel(
    const f32x2* __restrict__ ck,
    int* __restrict__ idx_out, float* __restrict__ w_out) {
    size_t p = (size_t)blockIdx.x * 256 + threadIdx.x;
    float k0 = 3.4e38f, k1 = 3.4e38f, k2 = 3.4e38f;
    int i0 = 0, i1 = 0, i2 = 0;
#pragma unroll
    for (int part = 0; part < SPLIT; ++part) {
#pragma unroll
        for (int rank = 0; rank < 3; ++rank) {
            f32x2 e = __builtin_nontemporal_load(ck + (size_t)(rank * SPLIT + part) * BNTOT + p);
            float x = e[0];
            int ix = __float_as_int(e[1]);
            bool c0 = x < k0, c1 = x < k1, c2 = x < k2;
            float mx = c0 ? k0 : x;  int mxi = c0 ? i0 : ix;
            float m2 = c1 ? k1 : x;  int m2i = c1 ? i1 : ix;
            k0 = c0 ? x : k0;   i0 = c0 ? ix : i0;
            k1 = c1 ? mx : k1;  i1 = c1 ? mxi : i1;
            k2 = c2 ? m2 : k2;  i2 = c2 ? m2i : i2;
        }
    }
    float w0 = 1.0f / (k0 + 1e-8f);
    float w1 = 1.0f / (k1 + 1e-8f);
    float w2 = 1.0f / (k2 + 1e-8f);
    float ws = w0 + w1 + w2;
    w0 /= ws; w1 /= ws; w2 /= ws;
    idx_out[p * 3 + 0] = i0; idx_out[p * 3 + 1] = i1; idx_out[p * 3 + 2] = i2;
    w_out[p * 3 + 0] = w0;  w_out[p * 3 + 1] = w1;  w_out[p * 3 + 2] = w2;
}

// ---------------- kernel: gather-interp + concat -> x0 (fp16) ----------------
// One wave per point. pts1 / x0 use nontemporal (streamed once) so the
// streaming traffic doesn't evict pts2 gather rows from L2.
__global__ __launch_bounds__(256) void interp_kernel(
    const float* __restrict__ pts1, const float* __restrict__ pts2,
    const int* __restrict__ idxb, const float* __restrict__ wb,
    f16* __restrict__ x0) {
    int wave = threadIdx.x >> 6, lane = threadIdx.x & 63;
    size_t p = (size_t)blockIdx.x * 4 + wave;
    int batch = (int)(p >> 14);  // N_=16384
    int j0 = idxb[p * 3 + 0], j1 = idxb[p * 3 + 1], j2 = idxb[p * 3 + 2];
    float w0 = wb[p * 3 + 0], w1 = wb[p * 3 + 1], w2 = wb[p * 3 + 2];
    const float* base2 = pts2 + (size_t)batch * M_ * C2_;
    f32x4 a = *(const f32x4*)(base2 + (size_t)j0 * C2_ + lane * 4);
    f32x4 bv = *(const f32x4*)(base2 + (size_t)j1 * C2_ + lane * 4);
    f32x4 c = *(const f32x4*)(base2 + (size_t)j2 * C2_ + lane * 4);
    f16* xrow = x0 + p * (C1_ + C2_);
    f16x4 o;
#pragma unroll
    for (int j = 0; j < 4; ++j)
        o[j] = (f16)(w0 * a[j] + w1 * bv[j] + w2 * c[j]);
    __builtin_nontemporal_store(o, (f16x4*)(xrow + C1_ + lane * 4));
    f32x2 p1 = __builtin_nontemporal_load((const f32x2*)(pts1 + p * C1_ + lane * 2));
    f16x2 o2; o2[0] = (f16)p1[0]; o2[1] = (f16)p1[1];
    __builtin_nontemporal_store(o2, (f16x2*)(xrow + lane * 2));
}

// ---------------- kernel: fp16 GEMM + fused BN-stats epilogue ----------------
// H[m][o] = sum_c A[m][c] * W[o][c]. 128x128 tile, BK=64, 4 waves (2x2),
// global_load_lds staging. Epilogue also accumulates per-channel sum/sumsq
// (on fp32 acc, pre-f16-rounding) via shfl_xor reduce + atomics.
template <int K>
__global__ __launch_bounds__(256) void gemm_f16(
    const f16* __restrict__ A, const f16* __restrict__ W,
    f16* __restrict__ H, float* __restrict__ sums, float* __restrict__ sumsq,
    int Nn) {
    __shared__ __align__(16) f16 As[128 * 64];
    __shared__ __align__(16) f16 Bs[128 * 64];
    int tid = threadIdx.x;
    int lane = tid & 63, wave = tid >> 6;
    int wr = wave >> 1, wc = wave & 1;
    int bm0 = blockIdx.x * 128, bn0 = blockIdx.y * 128;
    const f16* Ab = A + (size_t)bm0 * K;
    const f16* Wb = W + (size_t)bn0 * K;
    int r = tid >> 3;            // 0..31
    int cc = (tid & 7) * 8;      // 0..56, 8 f16 = 16B
    f32x4 acc[4][4] = {};
    for (int kt = 0; kt < K; kt += 64) {
        __syncthreads();
#pragma unroll
        for (int i = 0; i < 4; ++i) {
            gload_lds16(Ab + (size_t)(i * 32 + r) * K + kt + cc, &As[(i * 32 + r) * 64 + cc]);
            gload_lds16(Wb + (size_t)(i * 32 + r) * K + kt + cc, &Bs[(i * 32 + r) * 64 + cc]);
        }
        __syncthreads();
#pragma unroll
        for (int kk = 0; kk < 2; ++kk) {
            f16x8 af[4], bf[4];
            int koff = kk * 32 + (lane >> 4) * 8;
#pragma unroll
            for (int mt = 0; mt < 4; ++mt)
                af[mt] = *(const f16x8*)&As[(wr * 64 + mt * 16 + (lane & 15)) * 64 + koff];
#pragma unroll
            for (int nt = 0; nt < 4; ++nt)
                bf[nt] = *(const f16x8*)&Bs[(wc * 64 + nt * 16 + (lane & 15)) * 64 + koff];
#pragma unroll
            for (int mt = 0; mt < 4; ++mt)
#pragma unroll
                for (int nt = 0; nt < 4; ++nt)
                    acc[mt][nt] = __builtin_amdgcn_mfma_f32_16x16x32_f16(af[mt], bf[nt], acc[mt][nt], 0, 0, 0);
        }
    }
    // epilogue: C/D layout col=lane&15, row=(lane>>4)*4+reg
    int rr = (lane >> 4) * 4;
    int cl = lane & 15;
#pragma unroll
    for (int mt = 0; mt < 4; ++mt) {
#pragma unroll
        for (int nt = 0; nt < 4; ++nt) {
            int row = bm0 + wr * 64 + mt * 16 + rr;
            int col = bn0 + wc * 64 + nt * 16 + cl;
#pragma unroll
            for (int j = 0; j < 4; ++j)
                H[(size_t)(row + j) * Nn + col] = (f16)acc[mt][nt][j];
        }
    }
    // fused per-channel stats: this wave's 64 rows of 16 cols per nt.
    // 4 lane-groups (lane>>4) hold the same col -> butterfly combine.
#pragma unroll
    for (int nt = 0; nt < 4; ++nt) {
        float s = 0.f, s2 = 0.f;
#pragma unroll
        for (int mt = 0; mt < 4; ++mt)
#pragma unroll
            for (int j = 0; j < 4; ++j) {
                float v = acc[mt][nt][j];
                s += v;
                s2 = fmaf(v, v, s2);
            }
        s += __shfl_xor(s, 16);
        s2 += __shfl_xor(s2, 16);
        s += __shfl_xor(s, 32);
        s2 += __shfl_xor(s2, 32);
        if (lane < 16) {
            int c = bn0 + wc * 64 + nt * 16 + lane;
            atomicAdd(&sums[c], s);
            atomicAdd(&sumsq[c], s2);
        }
    }
}

// ---------------- kernel: BN finalize + apply + ReLU (fused) ----------------
// Each block recomputes scale/shift for its channels into LDS, then applies.
template <bool OUT16>
__global__ __launch_bounds__(256) void bnrelu_kernel(
    const f16* __restrict__ H, const float* __restrict__ sums, const float* __restrict__ sumsq,
    const float* __restrict__ g, const float* __restrict__ be,
    f16* __restrict__ o16, float* __restrict__ o32, int Nn) {
    __shared__ float ssc[256], ssh[256];
    int tid = threadIdx.x;
    if (tid < Nn) {
        const float invM = 1.0f / 65536.0f;
        float mean = sums[tid] * invM;
        float var = sumsq[tid] * invM - mean * mean;
        float rstd = rsqrtf(var + 1e-5f);
        float sc = rstd * g[tid];
        ssc[tid] = sc;
        ssh[tid] = be[tid] - mean * sc;
    }
    __syncthreads();
    size_t t = (size_t)blockIdx.x * 256 + tid;
    size_t base = t * 8;
    int c0 = (int)(base & (size_t)(Nn - 1));
    f16x8 v = *(const f16x8*)(H + base);
    float r[8];
#pragma unroll
    for (int j = 0; j < 8; ++j)
        r[j] = fmaxf(0.0f, fmaf((float)v[j], ssc[c0 + j], ssh[c0 + j]));
    if (OUT16) {
        f16x8 ov;
#pragma unroll
        for (int j = 0; j < 8; ++j) ov[j] = (f16)r[j];
        *(f16x8*)(o16 + base) = ov;
    } else {
        f32x4 a = {r[0], r[1], r[2], r[3]};
        f32x4 b = {r[4], r[5], r[6], r[7]};
        __builtin_nontemporal_store(a, (f32x4*)(o32 + base));
        __builtin_nontemporal_store(b, (f32x4*)(o32 + base + 4));
    }
}

extern "C" void kernel_launch(void* const* d_in, const int* in_sizes, int n_in,
                              void* d_out, int out_size, void* d_ws, size_t ws_size,
                              hipStream_t stream) {
    const float* xyz1 = (const float*)d_in[0];
    const float* xyz2 = (const float*)d_in[1];
    const float* pts1 = (const float*)d_in[2];
    const float* pts2 = (const float*)d_in[3];
    const float* w0f = (const float*)d_in[4];
    const float* g0 = (const float*)d_in[6];
    const float* be0 = (const float*)d_in[7];
    const float* w1f = (const float*)d_in[8];
    const float* g1 = (const float*)d_in[10];
    const float* be1 = (const float*)d_in[11];
    const float* w2f = (const float*)d_in[12];
    const float* g2 = (const float*)d_in[14];
    const float* be2 = (const float*)d_in[15];
    // biases b{li} cancel exactly under training-mode BN -> unused.

    char* ws = (char*)d_ws;
    // layout (bytes):
    //   x0  : [0, 50331648)              65536x384 f16; reused as bufB after layer0
    //   bufA: [50331648, +33554432)      65536x256 f16
    //         (candidate buffer ck aliases bufA: dead before layer-0 GEMM;
    //          3*16*65536*8B = 25.2MB < 33.5MB)
    //   wb  : [83886080, +393216)        all three weight matrices, f16
    //   idx : [84279296, +786432)        65536x3 i32
    //   wgt : [85065728, +786432)        65536x3 f32
    //   stat: [85852160, +6144)          3 layers x (sums[256]+sumsq[256]) f32
    f16* x0 = (f16*)(ws + 0);
    f16* bufA = (f16*)(ws + 50331648);
    f16* bufB = x0;  // alias: x0 dead after layer-0 GEMM
    f32x2* ck = (f32x2*)(ws + 50331648);
    f16* wb0 = (f16*)(ws + 83886080);
    f16* wb1 = wb0 + 98304;
    f16* wb2 = wb1 + 65536;
    int* idxb = (int*)(ws + 84279296);
    float* wgt = (float*)(ws + 85065728);
    float* stats = (float*)(ws + 85852160);
    float* sums0 = stats,        *sumsq0 = stats + 256;
    float* sums1 = stats + 512,  *sumsq1 = stats + 768;
    float* sums2 = stats + 1024, *sumsq2 = stats + 1280;

    // weights -> fp16, stats buffers -> 0 (single kernel)
    conv_f16_kernel<<<384, 256, 0, stream>>>(w0f, wb0, w1f, wb1, w2f, wb2, stats);

    // 3-NN (split-M exact scan, QPT=4 register-blocked + merge) + interp/concat
    nn_part_kernel<<<(BNTOT / (256 * QPT)) * SPLIT, 256, 0, stream>>>(xyz1, xyz2, ck);
    nn_merge_kernel<<<BNTOT / 256, 256, 0, stream>>>(ck, idxb, wgt);
    interp_kernel<<<BNTOT / 4, 256, 0, stream>>>(pts1, pts2, idxb, wgt, x0);

    // ---- layer 0: 384 -> 256 ----
    gemm_f16<384><<<dim3(512, 2), 256, 0, stream>>>(x0, wb0, bufA, sums0, sumsq0, 256);
    bnrelu_kernel<true><<<8192, 256, 0, stream>>>(bufA, sums0, sumsq0, g0, be0, bufA, nullptr, 256);

    // ---- layer 1: 256 -> 256 ----
    gemm_f16<256><<<dim3(512, 2), 256, 0, stream>>>(bufA, wb1, bufB, sums1, sumsq1, 256);
    bnrelu_kernel<true><<<8192, 256, 0, stream>>>(bufB, sums1, sumsq1, g1, be1, bufB, nullptr, 256);

    // ---- layer 2: 256 -> 128 ----
    gemm_f16<256><<<dim3(512, 1), 256, 0, stream>>>(bufB, wb2, bufA, sums2, sumsq2, 128);
    bnrelu_kernel<false><<<4096, 256, 0, stream>>>(bufA, sums2, sumsq2, g2, be2, nullptr, (float*)d_out, 128);
}

// Round 10
// 424.300 us; speedup vs baseline: 1.2396x; 1.2396x over previous
//
#include <hip/hip_runtime.h>
#include <hip/hip_fp16.h>
#include <stdint.h>

typedef _Float16 f16;
typedef _Float16 f16x8 __attribute__((ext_vector_type(8)));
typedef _Float16 f16x4 __attribute__((ext_vector_type(4)));
typedef _Float16 f16x2 __attribute__((ext_vector_type(2)));
typedef float f32x4 __attribute__((ext_vector_type(4)));
typedef float f32x2 __attribute__((ext_vector_type(2)));

#define B_ 4
#define N_ 16384
#define M_ 4096
#define C1_ 128
#define C2_ 256
#define BNTOT 65536  // B_*N_

#define SPLIT 16
#define CHUNK (M_ / SPLIT)  // 256
#define QPT 2               // queries per thread: grid 2048 = 8 blocks/CU
                            // (R9 lesson: QPT=4 -> 4 blocks/CU -> 16 waves/CU
                            //  halved occupancy and doubled time)

// ---------------- async global->LDS 16B ----------------
__device__ __forceinline__ void gload_lds16(const void* g, void* l) {
    __builtin_amdgcn_global_load_lds(
        (const __attribute__((address_space(1))) void*)g,
        (__attribute__((address_space(3))) void*)l, 16, 0, 0);
}

// exact branchy top-3 insert (R2/R8-proven; strict < == lax.top_k tie-break)
#define NN_INSERT(k0, k1, k2, i0, i1, i2, d2, mi)                          \
    if (d2 < k2) {                                                         \
        if (d2 < k1) {                                                     \
            k2 = k1; i2 = i1;                                              \
            if (d2 < k0) { k1 = k0; i1 = i0; k0 = d2; i0 = mi; }           \
            else         { k1 = d2; i1 = mi; }                             \
        } else { k2 = d2; i2 = mi; }                                       \
    }

// ---------------- kernel: fp32 -> fp16 weights + zero stats buffers ----------------
__global__ void conv_f16_kernel(const float* __restrict__ s0, f16* __restrict__ d0,
                                const float* __restrict__ s1, f16* __restrict__ d1,
                                const float* __restrict__ s2, f16* __restrict__ d2,
                                float* __restrict__ statz) {
    int i = blockIdx.x * blockDim.x + threadIdx.x;
    if (i < 98304) d0[i] = (f16)s0[i];
    if (i < 65536) d1[i] = (f16)s1[i];
    if (i < 32768) d2[i] = (f16)s2[i];
    if (i < 1536) statz[i] = 0.0f;   // 3 layers x (sums[256], sumsq[256])
}

// ---------------- kernel: 3-NN partial search over one M-chunk ----------------
// EXACT fp32 d2 compares (packed-key truncation fatal in R5). QPT=2 queries
// per thread amortize the 3 ds_read_b128 over 8 evals while keeping grid
// 2048 = 8 blocks/CU = full 32 waves/CU. Direct squared-diff (no cancel).
__global__ __launch_bounds__(256) void nn_part_kernel(
    const float* __restrict__ xyz1, const float* __restrict__ xyz2,
    f32x2* __restrict__ ck) {
    __shared__ __align__(16) float xs[CHUNK];
    __shared__ __align__(16) float ys[CHUNK];
    __shared__ __align__(16) float zs[CHUNK];
    int bid = blockIdx.x;                // grid = (BNTOT/512) * SPLIT = 2048
    int part = bid & (SPLIT - 1);
    int pblk = bid >> 4;                 // 0..127, 512 queries each
    int b = pblk >> 5;                   // 32 point-blocks per batch
    int m0 = part * CHUNK;
    const float* x2 = xyz2 + ((size_t)b * M_ + m0) * 3;
    {
        int m = threadIdx.x;  // CHUNK == blockDim.x
        xs[m] = x2[m * 3 + 0];
        ys[m] = x2[m * 3 + 1];
        zs[m] = x2[m * 3 + 2];
    }
    __syncthreads();
    size_t p0 = (size_t)pblk * 512 + threadIdx.x;  // queries p0, p0+256
    const float* q0p = xyz1 + p0 * 3;
    const float* q1p = xyz1 + (p0 + 256) * 3;
    float q0x = q0p[0], q0y = q0p[1], q0z = q0p[2];
    float q1x = q1p[0], q1y = q1p[1], q1z = q1p[2];
    float a0 = 3.4e38f, a1 = 3.4e38f, a2 = 3.4e38f;
    float b0 = 3.4e38f, b1 = 3.4e38f, b2 = 3.4e38f;
    int ai0 = 0, ai1 = 0, ai2 = 0;
    int bi0 = 0, bi1 = 0, bi2 = 0;
    for (int m = 0; m < CHUNK; m += 4) {
        f32x4 xv = *(const f32x4*)&xs[m];   // uniform addr -> LDS broadcast
        f32x4 yv = *(const f32x4*)&ys[m];
        f32x4 zv = *(const f32x4*)&zs[m];
#pragma unroll
        for (int u = 0; u < 4; ++u) {
            float cx = xv[u], cy = yv[u], cz = zv[u];
            int mi = m0 + m + u;
            {
                float dx = q0x - cx, dy = q0y - cy, dz = q0z - cz;
                float d2 = fmaf(dx, dx, fmaf(dy, dy, dz * dz));
                NN_INSERT(a0, a1, a2, ai0, ai1, ai2, d2, mi)
            }
            {
                float dx = q1x - cx, dy = q1y - cy, dz = q1z - cz;
                float d2 = fmaf(dx, dx, fmaf(dy, dy, dz * dz));
                NN_INSERT(b0, b1, b2, bi0, bi1, bi2, d2, mi)
            }
        }
    }
    // rank-major [rank][part][point] -> each store fully coalesced (8B/lane)
    f32x2 e;
    e[0] = a0; e[1] = __int_as_float(ai0);
    __builtin_nontemporal_store(e, ck + (size_t)(0 * SPLIT + part) * BNTOT + p0);
    e[0] = a1; e[1] = __int_as_float(ai1);
    __builtin_nontemporal_store(e, ck + (size_t)(1 * SPLIT + part) * BNTOT + p0);
    e[0] = a2; e[1] = __int_as_float(ai2);
    __builtin_nontemporal_store(e, ck + (size_t)(2 * SPLIT + part) * BNTOT + p0);
    e[0] = b0; e[1] = __int_as_float(bi0);
    __builtin_nontemporal_store(e, ck + (size_t)(0 * SPLIT + part) * BNTOT + p0 + 256);
    e[0] = b1; e[1] = __int_as_float(bi1);
    __builtin_nontemporal_store(e, ck + (size_t)(1 * SPLIT + part) * BNTOT + p0 + 256);
    e[0] = b2; e[1] = __int_as_float(bi2);
    __builtin_nontemporal_store(e, ck + (size_t)(2 * SPLIT + part) * BNTOT + p0 + 256);
}

// ---------------- kernel: merge SPLIT x 3 candidates -> top-3 + weights ----------------
// Parts ascending, ranks ascending within part, strict < insertion ->
// identical result/tie-break to one sequential ascending-index scan.
__global__ __launch_bounds__(256) void nn_merge_kernel(
    const f32x2* __restrict__ ck,
    int* __restrict__ idx_out, float* __restrict__ w_out) {
    size_t p = (size_t)blockIdx.x * 256 + threadIdx.x;
    float k0 = 3.4e38f, k1 = 3.4e38f, k2 = 3.4e38f;
    int i0 = 0, i1 = 0, i2 = 0;
#pragma unroll
    for (int part = 0; part < SPLIT; ++part) {
#pragma unroll
        for (int rank = 0; rank < 3; ++rank) {
            f32x2 e = __builtin_nontemporal_load(ck + (size_t)(rank * SPLIT + part) * BNTOT + p);
            float x = e[0];
            int ix = __float_as_int(e[1]);
            bool c0 = x < k0, c1 = x < k1, c2 = x < k2;
            float mx = c0 ? k0 : x;  int mxi = c0 ? i0 : ix;
            float m2 = c1 ? k1 : x;  int m2i = c1 ? i1 : ix;
            k0 = c0 ? x : k0;   i0 = c0 ? ix : i0;
            k1 = c1 ? mx : k1;  i1 = c1 ? mxi : i1;
            k2 = c2 ? m2 : k2;  i2 = c2 ? m2i : i2;
        }
    }
    float w0 = 1.0f / (k0 + 1e-8f);
    float w1 = 1.0f / (k1 + 1e-8f);
    float w2 = 1.0f / (k2 + 1e-8f);
    float ws = w0 + w1 + w2;
    w0 /= ws; w1 /= ws; w2 /= ws;
    idx_out[p * 3 + 0] = i0; idx_out[p * 3 + 1] = i1; idx_out[p * 3 + 2] = i2;
    w_out[p * 3 + 0] = w0;  w_out[p * 3 + 1] = w1;  w_out[p * 3 + 2] = w2;
}

// ---------------- kernel: gather-interp + concat -> x0 (fp16) ----------------
// One wave per point. pts1 / x0 use nontemporal (streamed once) so the
// streaming traffic doesn't evict pts2 gather rows from L2.
__global__ __launch_bounds__(256) void interp_kernel(
    const float* __restrict__ pts1, const float* __restrict__ pts2,
    const int* __restrict__ idxb, const float* __restrict__ wb,
    f16* __restrict__ x0) {
    int wave = threadIdx.x >> 6, lane = threadIdx.x & 63;
    size_t p = (size_t)blockIdx.x * 4 + wave;
    int batch = (int)(p >> 14);  // N_=16384
    int j0 = idxb[p * 3 + 0], j1 = idxb[p * 3 + 1], j2 = idxb[p * 3 + 2];
    float w0 = wb[p * 3 + 0], w1 = wb[p * 3 + 1], w2 = wb[p * 3 + 2];
    const float* base2 = pts2 + (size_t)batch * M_ * C2_;
    f32x4 a = *(const f32x4*)(base2 + (size_t)j0 * C2_ + lane * 4);
    f32x4 bv = *(const f32x4*)(base2 + (size_t)j1 * C2_ + lane * 4);
    f32x4 c = *(const f32x4*)(base2 + (size_t)j2 * C2_ + lane * 4);
    f16* xrow = x0 + p * (C1_ + C2_);
    f16x4 o;
#pragma unroll
    for (int j = 0; j < 4; ++j)
        o[j] = (f16)(w0 * a[j] + w1 * bv[j] + w2 * c[j]);
    __builtin_nontemporal_store(o, (f16x4*)(xrow + C1_ + lane * 4));
    f32x2 p1 = __builtin_nontemporal_load((const f32x2*)(pts1 + p * C1_ + lane * 2));
    f16x2 o2; o2[0] = (f16)p1[0]; o2[1] = (f16)p1[1];
    __builtin_nontemporal_store(o2, (f16x2*)(xrow + lane * 2));
}

// ---------------- kernel: fp16 GEMM + fused BN-stats epilogue ----------------
// H[m][o] = sum_c A[m][c] * W[o][c]. 128x128 tile, BK=64, 4 waves (2x2),
// global_load_lds staging. Epilogue also accumulates per-channel sum/sumsq
// (on fp32 acc, pre-f16-rounding) via shfl_xor reduce + atomics.
template <int K>
__global__ __launch_bounds__(256) void gemm_f16(
    const f16* __restrict__ A, const f16* __restrict__ W,
    f16* __restrict__ H, float* __restrict__ sums, float* __restrict__ sumsq,
    int Nn) {
    __shared__ __align__(16) f16 As[128 * 64];
    __shared__ __align__(16) f16 Bs[128 * 64];
    int tid = threadIdx.x;
    int lane = tid & 63, wave = tid >> 6;
    int wr = wave >> 1, wc = wave & 1;
    int bm0 = blockIdx.x * 128, bn0 = blockIdx.y * 128;
    const f16* Ab = A + (size_t)bm0 * K;
    const f16* Wb = W + (size_t)bn0 * K;
    int r = tid >> 3;            // 0..31
    int cc = (tid & 7) * 8;      // 0..56, 8 f16 = 16B
    f32x4 acc[4][4] = {};
    for (int kt = 0; kt < K; kt += 64) {
        __syncthreads();
#pragma unroll
        for (int i = 0; i < 4; ++i) {
            gload_lds16(Ab + (size_t)(i * 32 + r) * K + kt + cc, &As[(i * 32 + r) * 64 + cc]);
            gload_lds16(Wb + (size_t)(i * 32 + r) * K + kt + cc, &Bs[(i * 32 + r) * 64 + cc]);
        }
        __syncthreads();
#pragma unroll
        for (int kk = 0; kk < 2; ++kk) {
            f16x8 af[4], bf[4];
            int koff = kk * 32 + (lane >> 4) * 8;
#pragma unroll
            for (int mt = 0; mt < 4; ++mt)
                af[mt] = *(const f16x8*)&As[(wr * 64 + mt * 16 + (lane & 15)) * 64 + koff];
#pragma unroll
            for (int nt = 0; nt < 4; ++nt)
                bf[nt] = *(const f16x8*)&Bs[(wc * 64 + nt * 16 + (lane & 15)) * 64 + koff];
#pragma unroll
            for (int mt = 0; mt < 4; ++mt)
#pragma unroll
                for (int nt = 0; nt < 4; ++nt)
                    acc[mt][nt] = __builtin_amdgcn_mfma_f32_16x16x32_f16(af[mt], bf[nt], acc[mt][nt], 0, 0, 0);
        }
    }
    // epilogue: C/D layout col=lane&15, row=(lane>>4)*4+reg
    int rr = (lane >> 4) * 4;
    int cl = lane & 15;
#pragma unroll
    for (int mt = 0; mt < 4; ++mt) {
#pragma unroll
        for (int nt = 0; nt < 4; ++nt) {
            int row = bm0 + wr * 64 + mt * 16 + rr;
            int col = bn0 + wc * 64 + nt * 16 + cl;
#pragma unroll
            for (int j = 0; j < 4; ++j)
                H[(size_t)(row + j) * Nn + col] = (f16)acc[mt][nt][j];
        }
    }
    // fused per-channel stats: this wave's 64 rows of 16 cols per nt.
    // 4 lane-groups (lane>>4) hold the same col -> butterfly combine.
#pragma unroll
    for (int nt = 0; nt < 4; ++nt) {
        float s = 0.f, s2 = 0.f;
#pragma unroll
        for (int mt = 0; mt < 4; ++mt)
#pragma unroll
            for (int j = 0; j < 4; ++j) {
                float v = acc[mt][nt][j];
                s += v;
                s2 = fmaf(v, v, s2);
            }
        s += __shfl_xor(s, 16);
        s2 += __shfl_xor(s2, 16);
        s += __shfl_xor(s, 32);
        s2 += __shfl_xor(s2, 32);
        if (lane < 16) {
            int c = bn0 + wc * 64 + nt * 16 + lane;
            atomicAdd(&sums[c], s);
            atomicAdd(&sumsq[c], s2);
        }
    }
}

// ---------------- kernel: BN finalize + apply + ReLU (fused) ----------------
// Each block recomputes scale/shift for its channels into LDS, then applies.
template <bool OUT16>
__global__ __launch_bounds__(256) void bnrelu_kernel(
    const f16* __restrict__ H, const float* __restrict__ sums, const float* __restrict__ sumsq,
    const float* __restrict__ g, const float* __restrict__ be,
    f16* __restrict__ o16, float* __restrict__ o32, int Nn) {
    __shared__ float ssc[256], ssh[256];
    int tid = threadIdx.x;
    if (tid < Nn) {
        const float invM = 1.0f / 65536.0f;
        float mean = sums[tid] * invM;
        float var = sumsq[tid] * invM - mean * mean;
        float rstd = rsqrtf(var + 1e-5f);
        float sc = rstd * g[tid];
        ssc[tid] = sc;
        ssh[tid] = be[tid] - mean * sc;
    }
    __syncthreads();
    size_t t = (size_t)blockIdx.x * 256 + tid;
    size_t base = t * 8;
    int c0 = (int)(base & (size_t)(Nn - 1));
    f16x8 v = *(const f16x8*)(H + base);
    float r[8];
#pragma unroll
    for (int j = 0; j < 8; ++j)
        r[j] = fmaxf(0.0f, fmaf((float)v[j], ssc[c0 + j], ssh[c0 + j]));
    if (OUT16) {
        f16x8 ov;
#pragma unroll
        for (int j = 0; j < 8; ++j) ov[j] = (f16)r[j];
        *(f16x8*)(o16 + base) = ov;
    } else {
        f32x4 a = {r[0], r[1], r[2], r[3]};
        f32x4 b = {r[4], r[5], r[6], r[7]};
        __builtin_nontemporal_store(a, (f32x4*)(o32 + base));
        __builtin_nontemporal_store(b, (f32x4*)(o32 + base + 4));
    }
}

extern "C" void kernel_launch(void* const* d_in, const int* in_sizes, int n_in,
                              void* d_out, int out_size, void* d_ws, size_t ws_size,
                              hipStream_t stream) {
    const float* xyz1 = (const float*)d_in[0];
    const float* xyz2 = (const float*)d_in[1];
    const float* pts1 = (const float*)d_in[2];
    const float* pts2 = (const float*)d_in[3];
    const float* w0f = (const float*)d_in[4];
    const float* g0 = (const float*)d_in[6];
    const float* be0 = (const float*)d_in[7];
    const float* w1f = (const float*)d_in[8];
    const float* g1 = (const float*)d_in[10];
    const float* be1 = (const float*)d_in[11];
    const float* w2f = (const float*)d_in[12];
    const float* g2 = (const float*)d_in[14];
    const float* be2 = (const float*)d_in[15];
    // biases b{li} cancel exactly under training-mode BN -> unused.

    char* ws = (char*)d_ws;
    // layout (bytes):
    //   x0  : [0, 50331648)              65536x384 f16; reused as bufB after layer0
    //   bufA: [50331648, +33554432)      65536x256 f16
    //         (candidate buffer ck aliases bufA: dead before layer-0 GEMM;
    //          3*16*65536*8B = 25.2MB < 33.5MB)
    //   wb  : [83886080, +393216)        all three weight matrices, f16
    //   idx : [84279296, +786432)        65536x3 i32
    //   wgt : [85065728, +786432)        65536x3 f32
    //   stat: [85852160, +6144)          3 layers x (sums[256]+sumsq[256]) f32
    f16* x0 = (f16*)(ws + 0);
    f16* bufA = (f16*)(ws + 50331648);
    f16* bufB = x0;  // alias: x0 dead after layer-0 GEMM
    f32x2* ck = (f32x2*)(ws + 50331648);
    f16* wb0 = (f16*)(ws + 83886080);
    f16* wb1 = wb0 + 98304;
    f16* wb2 = wb1 + 65536;
    int* idxb = (int*)(ws + 84279296);
    float* wgt = (float*)(ws + 85065728);
    float* stats = (float*)(ws + 85852160);
    float* sums0 = stats,        *sumsq0 = stats + 256;
    float* sums1 = stats + 512,  *sumsq1 = stats + 768;
    float* sums2 = stats + 1024, *sumsq2 = stats + 1280;

    // weights -> fp16, stats buffers -> 0 (single kernel)
    conv_f16_kernel<<<384, 256, 0, stream>>>(w0f, wb0, w1f, wb1, w2f, wb2, stats);

    // 3-NN (split-M exact scan, QPT=2 @ 8 blocks/CU + merge) + interp/concat
    nn_part_kernel<<<(BNTOT / (256 * QPT)) * SPLIT, 256, 0, stream>>>(xyz1, xyz2, ck);
    nn_merge_kernel<<<BNTOT / 256, 256, 0, stream>>>(ck, idxb, wgt);
    interp_kernel<<<BNTOT / 4, 256, 0, stream>>>(pts1, pts2, idxb, wgt, x0);

    // ---- layer 0: 384 -> 256 ----
    gemm_f16<384><<<dim3(512, 2), 256, 0, stream>>>(x0, wb0, bufA, sums0, sumsq0, 256);
    bnrelu_kernel<true><<<8192, 256, 0, stream>>>(bufA, sums0, sumsq0, g0, be0, bufA, nullptr, 256);

    // ---- layer 1: 256 -> 256 ----
    gemm_f16<256><<<dim3(512, 2), 256, 0, stream>>>(bufA, wb1, bufB, sums1, sumsq1, 256);
    bnrelu_kernel<true><<<8192, 256, 0, stream>>>(bufB, sums1, sumsq1, g1, be1, bufB, nullptr, 256);

    // ---- layer 2: 256 -> 128 ----
    gemm_f16<256><<<dim3(512, 1), 256, 0, stream>>>(bufB, wb2, bufA, sums2, sumsq2, 128);
    bnrelu_kernel<false><<<4096, 256, 0, stream>>>(bufA, sums2, sumsq2, g2, be2, nullptr, (float*)d_out, 128);
}

// Round 11
// 403.213 us; speedup vs baseline: 1.3045x; 1.0523x over previous
//
#include <hip/hip_runtime.h>
#include <hip/hip_fp16.h>
#include <stdint.h>

typedef _Float16 f16;
typedef _Float16 f16x8 __attribute__((ext_vector_type(8)));
typedef _Float16 f16x4 __attribute__((ext_vector_type(4)));
typedef _Float16 f16x2 __attribute__((ext_vector_type(2)));
typedef float f32x4 __attribute__((ext_vector_type(4)));
typedef float f32x2 __attribute__((ext_vector_type(2)));

#define B_ 4
#define N_ 16384
#define M_ 4096
#define C1_ 128
#define C2_ 256
#define BNTOT 65536  // B_*N_

#define SPLIT 16
#define CHUNK (M_ / SPLIT)  // 256
#define QPT 2               // grid 2048 = 8 blocks/CU (R9: fewer halves perf)

// ---------------- async global->LDS 16B ----------------
__device__ __forceinline__ void gload_lds16(const void* g, void* l) {
    __builtin_amdgcn_global_load_lds(
        (const __attribute__((address_space(1))) void*)g,
        (__attribute__((address_space(3))) void*)l, 16, 0, 0);
}

// exact branchy top-3 insert (R2/R8-proven; strict < == lax.top_k tie-break)
#define NN_INSERT(k0, k1, k2, i0, i1, i2, d2, mi)                          \
    if (d2 < k2) {                                                         \
        if (d2 < k1) {                                                     \
            k2 = k1; i2 = i1;                                              \
            if (d2 < k0) { k1 = k0; i1 = i0; k0 = d2; i0 = mi; }           \
            else         { k1 = d2; i1 = mi; }                             \
        } else { k2 = d2; i2 = mi; }                                       \
    }

// ---------------- kernel: fp32 -> fp16 weights + zero stats buffers ----------------
__global__ void conv_f16_kernel(const float* __restrict__ s0, f16* __restrict__ d0,
                                const float* __restrict__ s1, f16* __restrict__ d1,
                                const float* __restrict__ s2, f16* __restrict__ d2,
                                float* __restrict__ statz) {
    int i = blockIdx.x * blockDim.x + threadIdx.x;
    if (i < 98304) d0[i] = (f16)s0[i];
    if (i < 65536) d1[i] = (f16)s1[i];
    if (i < 32768) d2[i] = (f16)s2[i];
    if (i < 1536) statz[i] = 0.0f;   // 3 layers x (sums[256], sumsq[256])
}

// ---------------- kernel: 3-NN partial search over one M-chunk ----------------
// Plateau'd at ~90us across QPT/CHUNK/insert variants (R2/R8/R10); exact
// fp32 d2 compares, branchy insert, QPT=2 @ 8 blocks/CU. Do not touch.
__global__ __launch_bounds__(256) void nn_part_kernel(
    const float* __restrict__ xyz1, const float* __restrict__ xyz2,
    f32x2* __restrict__ ck) {
    __shared__ __align__(16) float xs[CHUNK];
    __shared__ __align__(16) float ys[CHUNK];
    __shared__ __align__(16) float zs[CHUNK];
    int bid = blockIdx.x;                // grid = (BNTOT/512) * SPLIT = 2048
    int part = bid & (SPLIT - 1);
    int pblk = bid >> 4;                 // 0..127, 512 queries each
    int b = pblk >> 5;                   // 32 point-blocks per batch
    int m0 = part * CHUNK;
    const float* x2 = xyz2 + ((size_t)b * M_ + m0) * 3;
    {
        int m = threadIdx.x;  // CHUNK == blockDim.x
        xs[m] = x2[m * 3 + 0];
        ys[m] = x2[m * 3 + 1];
        zs[m] = x2[m * 3 + 2];
    }
    __syncthreads();
    size_t p0 = (size_t)pblk * 512 + threadIdx.x;  // queries p0, p0+256
    const float* q0p = xyz1 + p0 * 3;
    const float* q1p = xyz1 + (p0 + 256) * 3;
    float q0x = q0p[0], q0y = q0p[1], q0z = q0p[2];
    float q1x = q1p[0], q1y = q1p[1], q1z = q1p[2];
    float a0 = 3.4e38f, a1 = 3.4e38f, a2 = 3.4e38f;
    float b0 = 3.4e38f, b1 = 3.4e38f, b2 = 3.4e38f;
    int ai0 = 0, ai1 = 0, ai2 = 0;
    int bi0 = 0, bi1 = 0, bi2 = 0;
    for (int m = 0; m < CHUNK; m += 4) {
        f32x4 xv = *(const f32x4*)&xs[m];   // uniform addr -> LDS broadcast
        f32x4 yv = *(const f32x4*)&ys[m];
        f32x4 zv = *(const f32x4*)&zs[m];
#pragma unroll
        for (int u = 0; u < 4; ++u) {
            float cx = xv[u], cy = yv[u], cz = zv[u];
            int mi = m0 + m + u;
            {
                float dx = q0x - cx, dy = q0y - cy, dz = q0z - cz;
                float d2 = fmaf(dx, dx, fmaf(dy, dy, dz * dz));
                NN_INSERT(a0, a1, a2, ai0, ai1, ai2, d2, mi)
            }
            {
                float dx = q1x - cx, dy = q1y - cy, dz = q1z - cz;
                float d2 = fmaf(dx, dx, fmaf(dy, dy, dz * dz));
                NN_INSERT(b0, b1, b2, bi0, bi1, bi2, d2, mi)
            }
        }
    }
    // rank-major [rank][part][point] -> each store fully coalesced (8B/lane)
    f32x2 e;
    e[0] = a0; e[1] = __int_as_float(ai0);
    __builtin_nontemporal_store(e, ck + (size_t)(0 * SPLIT + part) * BNTOT + p0);
    e[0] = a1; e[1] = __int_as_float(ai1);
    __builtin_nontemporal_store(e, ck + (size_t)(1 * SPLIT + part) * BNTOT + p0);
    e[0] = a2; e[1] = __int_as_float(ai2);
    __builtin_nontemporal_store(e, ck + (size_t)(2 * SPLIT + part) * BNTOT + p0);
    e[0] = b0; e[1] = __int_as_float(bi0);
    __builtin_nontemporal_store(e, ck + (size_t)(0 * SPLIT + part) * BNTOT + p0 + 256);
    e[0] = b1; e[1] = __int_as_float(bi1);
    __builtin_nontemporal_store(e, ck + (size_t)(1 * SPLIT + part) * BNTOT + p0 + 256);
    e[0] = b2; e[1] = __int_as_float(bi2);
    __builtin_nontemporal_store(e, ck + (size_t)(2 * SPLIT + part) * BNTOT + p0 + 256);
}

// ---------------- kernel: merge SPLIT x 3 candidates -> top-3 + weights ----------------
__global__ __launch_bounds__(256) void nn_merge_kernel(
    const f32x2* __restrict__ ck,
    int* __restrict__ idx_out, float* __restrict__ w_out) {
    size_t p = (size_t)blockIdx.x * 256 + threadIdx.x;
    float k0 = 3.4e38f, k1 = 3.4e38f, k2 = 3.4e38f;
    int i0 = 0, i1 = 0, i2 = 0;
#pragma unroll
    for (int part = 0; part < SPLIT; ++part) {
#pragma unroll
        for (int rank = 0; rank < 3; ++rank) {
            f32x2 e = __builtin_nontemporal_load(ck + (size_t)(rank * SPLIT + part) * BNTOT + p);
            float x = e[0];
            int ix = __float_as_int(e[1]);
            bool c0 = x < k0, c1 = x < k1, c2 = x < k2;
            float mx = c0 ? k0 : x;  int mxi = c0 ? i0 : ix;
            float m2 = c1 ? k1 : x;  int m2i = c1 ? i1 : ix;
            k0 = c0 ? x : k0;   i0 = c0 ? ix : i0;
            k1 = c1 ? mx : k1;  i1 = c1 ? mxi : i1;
            k2 = c2 ? m2 : k2;  i2 = c2 ? m2i : i2;
        }
    }
    float w0 = 1.0f / (k0 + 1e-8f);
    float w1 = 1.0f / (k1 + 1e-8f);
    float w2 = 1.0f / (k2 + 1e-8f);
    float ws = w0 + w1 + w2;
    w0 /= ws; w1 /= ws; w2 /= ws;
    idx_out[p * 3 + 0] = i0; idx_out[p * 3 + 1] = i1; idx_out[p * 3 + 2] = i2;
    w_out[p * 3 + 0] = w0;  w_out[p * 3 + 1] = w1;  w_out[p * 3 + 2] = w2;
}

// ---------------- kernel: gather-interp + concat -> x0 (fp16) ----------------
__global__ __launch_bounds__(256) void interp_kernel(
    const float* __restrict__ pts1, const float* __restrict__ pts2,
    const int* __restrict__ idxb, const float* __restrict__ wb,
    f16* __restrict__ x0) {
    int wave = threadIdx.x >> 6, lane = threadIdx.x & 63;
    size_t p = (size_t)blockIdx.x * 4 + wave;
    int batch = (int)(p >> 14);  // N_=16384
    int j0 = idxb[p * 3 + 0], j1 = idxb[p * 3 + 1], j2 = idxb[p * 3 + 2];
    float w0 = wb[p * 3 + 0], w1 = wb[p * 3 + 1], w2 = wb[p * 3 + 2];
    const float* base2 = pts2 + (size_t)batch * M_ * C2_;
    f32x4 a = *(const f32x4*)(base2 + (size_t)j0 * C2_ + lane * 4);
    f32x4 bv = *(const f32x4*)(base2 + (size_t)j1 * C2_ + lane * 4);
    f32x4 c = *(const f32x4*)(base2 + (size_t)j2 * C2_ + lane * 4);
    f16* xrow = x0 + p * (C1_ + C2_);
    f16x4 o;
#pragma unroll
    for (int j = 0; j < 4; ++j)
        o[j] = (f16)(w0 * a[j] + w1 * bv[j] + w2 * c[j]);
    __builtin_nontemporal_store(o, (f16x4*)(xrow + C1_ + lane * 4));
    f32x2 p1 = __builtin_nontemporal_load((const f32x2*)(pts1 + p * C1_ + lane * 2));
    f16x2 o2; o2[0] = (f16)p1[0]; o2[1] = (f16)p1[1];
    __builtin_nontemporal_store(o2, (f16x2*)(xrow + lane * 2));
}

// ---------------- kernel: fp16 GEMM + fused BN-stats epilogue (layer 0) ----------------
template <int K>
__global__ __launch_bounds__(256) void gemm_f16(
    const f16* __restrict__ A, const f16* __restrict__ W,
    f16* __restrict__ H, float* __restrict__ sums, float* __restrict__ sumsq,
    int Nn) {
    __shared__ __align__(16) f16 As[128 * 64];
    __shared__ __align__(16) f16 Bs[128 * 64];
    int tid = threadIdx.x;
    int lane = tid & 63, wave = tid >> 6;
    int wr = wave >> 1, wc = wave & 1;
    int bm0 = blockIdx.x * 128, bn0 = blockIdx.y * 128;
    const f16* Ab = A + (size_t)bm0 * K;
    const f16* Wb = W + (size_t)bn0 * K;
    int r = tid >> 3;            // 0..31
    int cc = (tid & 7) * 8;      // 0..56, 8 f16 = 16B
    f32x4 acc[4][4] = {};
    for (int kt = 0; kt < K; kt += 64) {
        __syncthreads();
#pragma unroll
        for (int i = 0; i < 4; ++i) {
            gload_lds16(Ab + (size_t)(i * 32 + r) * K + kt + cc, &As[(i * 32 + r) * 64 + cc]);
            gload_lds16(Wb + (size_t)(i * 32 + r) * K + kt + cc, &Bs[(i * 32 + r) * 64 + cc]);
        }
        __syncthreads();
#pragma unroll
        for (int kk = 0; kk < 2; ++kk) {
            f16x8 af[4], bf[4];
            int koff = kk * 32 + (lane >> 4) * 8;
#pragma unroll
            for (int mt = 0; mt < 4; ++mt)
                af[mt] = *(const f16x8*)&As[(wr * 64 + mt * 16 + (lane & 15)) * 64 + koff];
#pragma unroll
            for (int nt = 0; nt < 4; ++nt)
                bf[nt] = *(const f16x8*)&Bs[(wc * 64 + nt * 16 + (lane & 15)) * 64 + koff];
#pragma unroll
            for (int mt = 0; mt < 4; ++mt)
#pragma unroll
                for (int nt = 0; nt < 4; ++nt)
                    acc[mt][nt] = __builtin_amdgcn_mfma_f32_16x16x32_f16(af[mt], bf[nt], acc[mt][nt], 0, 0, 0);
        }
    }
    int rr = (lane >> 4) * 4;
    int cl = lane & 15;
#pragma unroll
    for (int mt = 0; mt < 4; ++mt) {
#pragma unroll
        for (int nt = 0; nt < 4; ++nt) {
            int row = bm0 + wr * 64 + mt * 16 + rr;
            int col = bn0 + wc * 64 + nt * 16 + cl;
#pragma unroll
            for (int j = 0; j < 4; ++j)
                H[(size_t)(row + j) * Nn + col] = (f16)acc[mt][nt][j];
        }
    }
#pragma unroll
    for (int nt = 0; nt < 4; ++nt) {
        float s = 0.f, s2 = 0.f;
#pragma unroll
        for (int mt = 0; mt < 4; ++mt)
#pragma unroll
            for (int j = 0; j < 4; ++j) {
                float v = acc[mt][nt][j];
                s += v;
                s2 = fmaf(v, v, s2);
            }
        s += __shfl_xor(s, 16);
        s2 += __shfl_xor(s2, 16);
        s += __shfl_xor(s, 32);
        s2 += __shfl_xor(s2, 32);
        if (lane < 16) {
            int c = bn0 + wc * 64 + nt * 16 + lane;
            atomicAdd(&sums[c], s);
            atomicAdd(&sumsq[c], s2);
        }
    }
}

// ------ kernel: fused BN(prev)+ReLU on A-staging + GEMM + stats epilogue ------
// A = RAW previous-layer H (pre-BN f16). scale/shift computed from prev-layer
// sums/sumsq at kernel start (same formula as bnrelu); A staged via registers:
// f16 load -> fp32 fma+relu -> f16 round -> ds_write. Math byte-identical to
// the deleted separate bnrelu pass. W side keeps global_load_lds.
__global__ __launch_bounds__(256) void gemm_bn_f16(
    const f16* __restrict__ A, const float* __restrict__ psums,
    const float* __restrict__ psumsq, const float* __restrict__ pg,
    const float* __restrict__ pbe,
    const f16* __restrict__ W, f16* __restrict__ H,
    float* __restrict__ sums, float* __restrict__ sumsq, int Nn) {
    const int K = 256;
    __shared__ __align__(16) f16 As[128 * 64];
    __shared__ __align__(16) f16 Bs[128 * 64];
    __shared__ float ssc[K], ssh[K];
    int tid = threadIdx.x;
    {   // per-block BN finalize for the INPUT channels (K=256 == blockDim)
        const float invM = 1.0f / 65536.0f;
        float mean = psums[tid] * invM;
        float var = psumsq[tid] * invM - mean * mean;
        float rstd = rsqrtf(var + 1e-5f);
        float sc = rstd * pg[tid];
        ssc[tid] = sc;
        ssh[tid] = pbe[tid] - mean * sc;
    }
    int lane = tid & 63, wave = tid >> 6;
    int wr = wave >> 1, wc = wave & 1;
    int bm0 = blockIdx.x * 128, bn0 = blockIdx.y * 128;
    const f16* Ab = A + (size_t)bm0 * K;
    const f16* Wb = W + (size_t)bn0 * K;
    int r = tid >> 3;            // 0..31
    int cc = (tid & 7) * 8;      // 0..56
    f32x4 acc[4][4] = {};
    __syncthreads();             // ssc/ssh ready
    for (int kt = 0; kt < K; kt += 64) {
        __syncthreads();
#pragma unroll
        for (int i = 0; i < 4; ++i)
            gload_lds16(Wb + (size_t)(i * 32 + r) * K + kt + cc, &Bs[(i * 32 + r) * 64 + cc]);
#pragma unroll
        for (int i = 0; i < 4; ++i) {
            f16x8 v = *(const f16x8*)(Ab + (size_t)(i * 32 + r) * K + kt + cc);
            f16x8 o;
#pragma unroll
            for (int j = 0; j < 8; ++j)
                o[j] = (f16)fmaxf(0.0f, fmaf((float)v[j], ssc[kt + cc + j], ssh[kt + cc + j]));
            *(f16x8*)&As[(i * 32 + r) * 64 + cc] = o;
        }
        __syncthreads();
#pragma unroll
        for (int kk = 0; kk < 2; ++kk) {
            f16x8 af[4], bf[4];
            int koff = kk * 32 + (lane >> 4) * 8;
#pragma unroll
            for (int mt = 0; mt < 4; ++mt)
                af[mt] = *(const f16x8*)&As[(wr * 64 + mt * 16 + (lane & 15)) * 64 + koff];
#pragma unroll
            for (int nt = 0; nt < 4; ++nt)
                bf[nt] = *(const f16x8*)&Bs[(wc * 64 + nt * 16 + (lane & 15)) * 64 + koff];
#pragma unroll
            for (int mt = 0; mt < 4; ++mt)
#pragma unroll
                for (int nt = 0; nt < 4; ++nt)
                    acc[mt][nt] = __builtin_amdgcn_mfma_f32_16x16x32_f16(af[mt], bf[nt], acc[mt][nt], 0, 0, 0);
        }
    }
    int rr = (lane >> 4) * 4;
    int cl = lane & 15;
#pragma unroll
    for (int mt = 0; mt < 4; ++mt) {
#pragma unroll
        for (int nt = 0; nt < 4; ++nt) {
            int row = bm0 + wr * 64 + mt * 16 + rr;
            int col = bn0 + wc * 64 + nt * 16 + cl;
#pragma unroll
            for (int j = 0; j < 4; ++j)
                H[(size_t)(row + j) * Nn + col] = (f16)acc[mt][nt][j];
        }
    }
#pragma unroll
    for (int nt = 0; nt < 4; ++nt) {
        float s = 0.f, s2 = 0.f;
#pragma unroll
        for (int mt = 0; mt < 4; ++mt)
#pragma unroll
            for (int j = 0; j < 4; ++j) {
                float v = acc[mt][nt][j];
                s += v;
                s2 = fmaf(v, v, s2);
            }
        s += __shfl_xor(s, 16);
        s2 += __shfl_xor(s2, 16);
        s += __shfl_xor(s, 32);
        s2 += __shfl_xor(s2, 32);
        if (lane < 16) {
            int c = bn0 + wc * 64 + nt * 16 + lane;
            atomicAdd(&sums[c], s);
            atomicAdd(&sumsq[c], s2);
        }
    }
}

// ---------------- kernel: final BN + apply + ReLU -> fp32 out ----------------
__global__ __launch_bounds__(256) void bnrelu_f32_kernel(
    const f16* __restrict__ H, const float* __restrict__ sums, const float* __restrict__ sumsq,
    const float* __restrict__ g, const float* __restrict__ be,
    float* __restrict__ o32, int Nn) {
    __shared__ float ssc[256], ssh[256];
    int tid = threadIdx.x;
    if (tid < Nn) {
        const float invM = 1.0f / 65536.0f;
        float mean = sums[tid] * invM;
        float var = sumsq[tid] * invM - mean * mean;
        float rstd = rsqrtf(var + 1e-5f);
        float sc = rstd * g[tid];
        ssc[tid] = sc;
        ssh[tid] = be[tid] - mean * sc;
    }
    __syncthreads();
    size_t t = (size_t)blockIdx.x * 256 + tid;
    size_t base = t * 8;
    int c0 = (int)(base & (size_t)(Nn - 1));
    f16x8 v = *(const f16x8*)(H + base);
    float r[8];
#pragma unroll
    for (int j = 0; j < 8; ++j)
        r[j] = fmaxf(0.0f, fmaf((float)v[j], ssc[c0 + j], ssh[c0 + j]));
    f32x4 a = {r[0], r[1], r[2], r[3]};
    f32x4 b = {r[4], r[5], r[6], r[7]};
    __builtin_nontemporal_store(a, (f32x4*)(o32 + base));
    __builtin_nontemporal_store(b, (f32x4*)(o32 + base + 4));
}

extern "C" void kernel_launch(void* const* d_in, const int* in_sizes, int n_in,
                              void* d_out, int out_size, void* d_ws, size_t ws_size,
                              hipStream_t stream) {
    const float* xyz1 = (const float*)d_in[0];
    const float* xyz2 = (const float*)d_in[1];
    const float* pts1 = (const float*)d_in[2];
    const float* pts2 = (const float*)d_in[3];
    const float* w0f = (const float*)d_in[4];
    const float* g0 = (const float*)d_in[6];
    const float* be0 = (const float*)d_in[7];
    const float* w1f = (const float*)d_in[8];
    const float* g1 = (const float*)d_in[10];
    const float* be1 = (const float*)d_in[11];
    const float* w2f = (const float*)d_in[12];
    const float* g2 = (const float*)d_in[14];
    const float* be2 = (const float*)d_in[15];
    // biases b{li} cancel exactly under training-mode BN -> unused.

    char* ws = (char*)d_ws;
    // layout (bytes):
    //   x0  : [0, 50331648)              65536x384 f16; reused as H1 after layer0
    //   bufA: [50331648, +33554432)      65536x256 f16 (H0, then H2)
    //         (candidate buffer ck aliases bufA: dead before layer-0 GEMM)
    //   wb  : [83886080, +393216)        all three weight matrices, f16
    //   idx : [84279296, +786432)        65536x3 i32
    //   wgt : [85065728, +786432)        65536x3 f32
    //   stat: [85852160, +6144)          3 layers x (sums[256]+sumsq[256]) f32
    f16* x0 = (f16*)(ws + 0);
    f16* bufA = (f16*)(ws + 50331648);
    f16* bufB = x0;  // alias: x0 dead after layer-0 GEMM
    f32x2* ck = (f32x2*)(ws + 50331648);
    f16* wb0 = (f16*)(ws + 83886080);
    f16* wb1 = wb0 + 98304;
    f16* wb2 = wb1 + 65536;
    int* idxb = (int*)(ws + 84279296);
    float* wgt = (float*)(ws + 85065728);
    float* stats = (float*)(ws + 85852160);
    float* sums0 = stats,        *sumsq0 = stats + 256;
    float* sums1 = stats + 512,  *sumsq1 = stats + 768;
    float* sums2 = stats + 1024, *sumsq2 = stats + 1280;

    // weights -> fp16, stats buffers -> 0 (single kernel)
    conv_f16_kernel<<<384, 256, 0, stream>>>(w0f, wb0, w1f, wb1, w2f, wb2, stats);

    // 3-NN (split-M exact scan + merge) + interp/concat
    nn_part_kernel<<<(BNTOT / (256 * QPT)) * SPLIT, 256, 0, stream>>>(xyz1, xyz2, ck);
    nn_merge_kernel<<<BNTOT / 256, 256, 0, stream>>>(ck, idxb, wgt);
    interp_kernel<<<BNTOT / 4, 256, 0, stream>>>(pts1, pts2, idxb, wgt, x0);

    // ---- layer 0: 384 -> 256 (raw H0 + stats0) ----
    gemm_f16<384><<<dim3(512, 2), 256, 0, stream>>>(x0, wb0, bufA, sums0, sumsq0, 256);

    // ---- layer 1: BN0+ReLU fused into A-staging; 256 -> 256 (raw H1 + stats1) ----
    gemm_bn_f16<<<dim3(512, 2), 256, 0, stream>>>(bufA, sums0, sumsq0, g0, be0,
                                                  wb1, bufB, sums1, sumsq1, 256);

    // ---- layer 2: BN1+ReLU fused into A-staging; 256 -> 128 (raw H2 + stats2) ----
    gemm_bn_f16<<<dim3(512, 1), 256, 0, stream>>>(bufB, sums1, sumsq1, g1, be1,
                                                  wb2, bufA, sums2, sumsq2, 128);

    // ---- final BN2 + ReLU -> fp32 output ----
    bnrelu_f32_kernel<<<4096, 256, 0, stream>>>(bufA, sums2, sumsq2, g2, be2,
                                                (float*)d_out, 128);
}